// Round 5
// baseline (364.685 us; speedup 1.0000x reference)
//
#include <hip/hip_runtime.h>

// B=64, C=512, H=W=28, NL=4, fp32. Layer update is LINEAR per plane:
// x_4 = sum_{j=0..4} e_j K^j x_0 (K = zero-padded depthwise 3x3), e from cells.
// 3 dispatches: statsW (W_j in LDS + mu dot-products), cell_all (all 4 layers,
// batch-0 trajectory computed redundantly per block), mega (column-register Horner).

#define HW 784
#define F4 196
#define CC 512
#define BB 64
#define NP 32768
#define TS 31

__device__ __forceinline__ float sigm(float x) { return 1.f / (1.f + __expf(-x)); }

#define STENCIL(src, py, px4, w0,w1,w2,w3,w4,w5,w6,w7,w8, y0,y1,y2,y3) do { \
    const float* r0 = &(src)[(py) * TS + (px4) * 4]; \
    const float* r1 = r0 + TS; \
    const float* r2 = r0 + 2 * TS; \
    float a0=r0[0],a1=r0[1],a2=r0[2],a3=r0[3],a4=r0[4],a5=r0[5]; \
    float b0=r1[0],b1=r1[1],b2=r1[2],b3=r1[3],b4=r1[4],b5=r1[5]; \
    float c0=r2[0],c1=r2[1],c2=r2[2],c3=r2[3],c4=r2[4],c5=r2[5]; \
    y0 = a0*w0+a1*w1+a2*w2 + b0*w3+b1*w4+b2*w5 + c0*w6+c1*w7+c2*w8; \
    y1 = a1*w0+a2*w1+a3*w2 + b1*w3+b2*w4+b3*w5 + c1*w6+c2*w7+c3*w8; \
    y2 = a2*w0+a3*w1+a4*w2 + b2*w3+b3*w4+b4*w5 + c2*w6+c3*w7+c4*w8; \
    y3 = a3*w0+a4*w1+a5*w2 + b3*w3+b4*w4+b5*w5 + c3*w6+c4*w7+c5*w8; \
} while (0)

#define ZERO_HALO(tile) do { \
    if (t < 30) (tile)[t] = 0.f; \
    else if (t < 60) (tile)[29 * TS + (t - 30)] = 0.f; \
    else if (t < 88) (tile)[(t - 59) * TS] = 0.f; \
    else if (t < 116) (tile)[(t - 87) * TS + 29] = 0.f; \
} while (0)

// ---- statsW: W_j=(K^T)^j 1 in LDS, then mu_j = <x,W_j>/784 for 32 batches ----
// 1024 blocks: c = blk>>1, batches (blk&1)*32 .. +32
__global__ void __launch_bounds__(256) statsW_kernel(const float* __restrict__ x,
                                                     const float* __restrict__ dwk,
                                                     float* __restrict__ mu) {
    __shared__ float tA[30 * TS], tB[30 * TS];
    __shared__ float s_w[9];
    __shared__ __align__(16) float sW[3][HW];
    const int c = blockIdx.x >> 1, half = blockIdx.x & 1;
    const int t = threadIdx.x;
    ZERO_HALO(tA); ZERO_HALO(tB);
    if (t < 9) s_w[t] = dwk[c * 9 + 8 - t];   // flipped: K^T
    int py = t / 7, px4 = t - py * 7;
    if (t < F4) {
        float* d = &tA[(py + 1) * TS + px4 * 4 + 1];
        d[0] = d[1] = d[2] = d[3] = 1.f;
    }
    __syncthreads();
    {
        float w0=s_w[0],w1=s_w[1],w2=s_w[2],w3=s_w[3],w4=s_w[4],w5=s_w[5],w6=s_w[6],w7=s_w[7],w8=s_w[8];
        float* src = tA; float* dst = tB;
        for (int it = 1; it <= 3; ++it) {
            if (t < F4) {
                float y0, y1, y2, y3;
                STENCIL(src, py, px4, w0,w1,w2,w3,w4,w5,w6,w7,w8, y0,y1,y2,y3);
                float* d = &dst[(py + 1) * TS + px4 * 4 + 1];
                d[0]=y0; d[1]=y1; d[2]=y2; d[3]=y3;
                ((float4*)sW[it - 1])[t] = make_float4(y0, y1, y2, y3);
            }
            __syncthreads();
            float* tmp = src; src = dst; dst = tmp;
        }
    }
    // phase 2: one wave per plane, 8 rounds of 4 batches
    const int wave = t >> 6, lane = t & 63;
    for (int r = 0; r < 8; ++r) {
        int b = half * 32 + r * 4 + wave;
        const float4* xv = (const float4*)(x + (size_t)(b * CC + c) * HW);
        float s0 = 0.f, s1 = 0.f, s2 = 0.f, s3 = 0.f;
        for (int j = lane; j < F4; j += 64) {
            float4 v = xv[j];
            float4 a = ((const float4*)sW[0])[j];
            float4 bb = ((const float4*)sW[1])[j];
            float4 d = ((const float4*)sW[2])[j];
            s0 += v.x + v.y + v.z + v.w;
            s1 += v.x*a.x + v.y*a.y + v.z*a.z + v.w*a.w;
            s2 += v.x*bb.x + v.y*bb.y + v.z*bb.z + v.w*bb.w;
            s3 += v.x*d.x + v.y*d.y + v.z*d.z + v.w*d.w;
        }
        #pragma unroll
        for (int off = 32; off > 0; off >>= 1) {
            s0 += __shfl_down(s0, off, 64);
            s1 += __shfl_down(s1, off, 64);
            s2 += __shfl_down(s2, off, 64);
            s3 += __shfl_down(s3, off, 64);
        }
        if (lane == 0) {
            int p = b * CC + c;
            mu[p]          = s0 * (1.f / 784.f);
            mu[NP + p]     = s1 * (1.f / 784.f);
            mu[2 * NP + p] = s2 * (1.f / 784.f);
            mu[3 * NP + p] = s3 * (1.f / 784.f);
        }
    }
}

// ---- cell_all helpers ----
__device__ __forceinline__ float matvec32(const float* __restrict__ Wrow,
                                          const float* __restrict__ hid) {
    const float4* wv4 = (const float4*)Wrow;
    float acc = 0.f;
    #pragma unroll
    for (int j = 0; j < 8; ++j) {
        float4 w = wv4[j];
        acc += hid[4*j]*w.x + hid[4*j+1]*w.y + hid[4*j+2]*w.z + hid[4*j+3]*w.w;
    }
    return acc;
}
// 512 threads: 32 outputs x 16 lanes, relu(b + W.in)
__device__ __forceinline__ void stageA(const float* __restrict__ W,
                                       const float* __restrict__ bias,
                                       const float* __restrict__ in,
                                       float* __restrict__ hid, int t) {
    int o = t >> 4, q = t & 15;
    const float4* wv4 = (const float4*)(W + o * CC) + q * 8;
    const float4* in4 = (const float4*)in + q * 8;
    float acc = 0.f;
    #pragma unroll
    for (int j = 0; j < 8; ++j) {
        float4 w = wv4[j], xv = in4[j];
        acc += xv.x*w.x + xv.y*w.y + xv.z*w.z + xv.w*w.w;
    }
    acc += __shfl_down(acc, 8, 64);
    acc += __shfl_down(acc, 4, 64);
    acc += __shfl_down(acc, 2, 64);
    acc += __shfl_down(acc, 1, 64);
    if (q == 0) hid[o] = fmaxf(acc + bias[o], 0.f);
}

// ---- all 4 layers of cell math; 64 blocks x 512 thr; emits e0..e4 per plane ----
__global__ void __launch_bounds__(512) cell_all_kernel(
        const float* __restrict__ mu, float* __restrict__ e,
        const float* __restrict__ w_ih1, const float* __restrict__ b_ih1,
        const float* __restrict__ w_ih2, const float* __restrict__ b_ih2,
        const float* __restrict__ w_hh1, const float* __restrict__ b_hh1,
        const float* __restrict__ w_hh2, const float* __restrict__ b_hh2) {
    __shared__ __align__(16) float s_in[CC];
    __shared__ __align__(16) float s_h[CC];
    __shared__ float s_hid[32];
    __shared__ float s_gi[2][1536];   // ih gates: [0]=batch0, [1]=own
    __shared__ float s_ghp[2][1536];  // prev-layer hh gates
    __shared__ float s_gh2[1536];     // this layer's g_h2 = MLP_hh(h0_new)
    const int b = blockIdx.x, t = threadIdx.x;   // t == channel

    float mu0[4], mub[4];
    #pragma unroll
    for (int j = 0; j < 4; ++j) {
        mu0[j] = mu[j * NP + t];
        mub[j] = mu[j * NP + b * CC + t];
    }
    float cf0[4] = {1.f, 0.f, 0.f, 0.f};
    float cfb[4] = {1.f, 0.f, 0.f, 0.f};
    float ct0 = 0.f, ctb = 0.f;

    // init: g_h(ht=0) = W_hh2.relu(b_hh1)+b_hh2 into both ghp rows
    if (t < 32) s_hid[t] = fmaxf(b_hh1[t], 0.f);
    __syncthreads();
    for (int o = t; o < 1536; o += 512) {
        float acc = matvec32(w_hh2 + o * 32, s_hid) + b_hh2[o];
        s_ghp[0][o] = acc;
        s_ghp[1][o] = acc;
    }

    for (int k = 0; k < 4; ++k) {
        __syncthreads();                                              // S0
        // ===== batch-0 state cell =====
        s_in[t] = cf0[0]*mu0[0] + cf0[1]*mu0[1] + cf0[2]*mu0[2] + cf0[3]*mu0[3];
        __syncthreads();                                              // S1
        stageA(w_ih1, b_ih1, s_in, s_hid, t);
        __syncthreads();                                              // S2
        for (int o = t; o < 1536; o += 512)
            s_gi[0][o] = matvec32(w_ih2 + o * 32, s_hid) + b_ih2[o];
        __syncthreads();                                              // S3
        {
            float gi = s_gi[0][t]        + s_ghp[0][t];
            float gf = s_gi[0][CC + t]   + s_ghp[0][CC + t];
            float gc = s_gi[0][2*CC + t] + s_ghp[0][2*CC + t];
            float nc = sigm(gf) * ct0 + sigm(gi) * tanhf(gc);
            ct0 = nc;
            s_h[t] = sigm(nc);
        }
        __syncthreads();                                              // S4
        stageA(w_hh1, b_hh1, s_h, s_hid, t);
        __syncthreads();                                              // S5
        for (int o = t; o < 1536; o += 512)
            s_gh2[o] = matvec32(w_hh2 + o * 32, s_hid) + b_hh2[o];
        __syncthreads();                                              // S6
        // ===== own-batch state cell =====
        s_in[t] = cfb[0]*mub[0] + cfb[1]*mub[1] + cfb[2]*mub[2] + cfb[3]*mub[3];
        __syncthreads();                                              // S7
        stageA(w_ih1, b_ih1, s_in, s_hid, t);
        __syncthreads();                                              // S8
        for (int o = t; o < 1536; o += 512)
            s_gi[1][o] = matvec32(w_ih2 + o * 32, s_hid) + b_ih2[o];
        __syncthreads();                                              // S9
        {
            float gi = s_gi[1][t]        + s_ghp[1][t];
            float gf = s_gi[1][CC + t]   + s_ghp[1][CC + t];
            float gc = s_gi[1][2*CC + t] + s_ghp[1][2*CC + t];
            float nc = sigm(gf) * ctb + sigm(gi) * tanhf(gc);
            ctb = nc;
            s_h[t] = sigm(nc);
        }
        __syncthreads();                                              // S10
        stageA(w_hh1, b_hh1, s_h, s_hid, t);
        __syncthreads();                                              // S11
        for (int o = t; o < 1536; o += 512)
            s_ghp[1][o] = matvec32(w_hh2 + o * 32, s_hid) + b_hh2[o]; // own g_hpre (next layer)
        // ===== A_k (cell-2 gates: uses batch-0's NEW ct and g_h2) =====
        {
            float f0 = s_gi[0][CC + t] + s_gh2[CC + t];
            float i0 = s_gi[0][t]      + s_gh2[t];
            float c0g = s_gi[0][2*CC + t] + s_gh2[2*CC + t];
            float A0 = 1.f + sigm(sigm(f0) * ct0 + sigm(i0) * tanhf(c0g));
            float fb = s_gi[1][CC + t] + s_gh2[CC + t];
            float ib = s_gi[1][t]      + s_gh2[t];
            float cbg = s_gi[1][2*CC + t] + s_gh2[2*CC + t];
            float Ab = 1.f + sigm(sigm(fb) * ct0 + sigm(ib) * tanhf(cbg));
            if (k < 3) {
                cf0[3] = A0*cf0[3] + cf0[2]; cf0[2] = A0*cf0[2] + cf0[1];
                cf0[1] = A0*cf0[1] + cf0[0]; cf0[0] = A0*cf0[0];
                cfb[3] = Ab*cfb[3] + cfb[2]; cfb[2] = Ab*cfb[2] + cfb[1];
                cfb[1] = Ab*cfb[1] + cfb[0]; cfb[0] = Ab*cfb[0];
            } else {
                int p = b * CC + t;
                e[4 * NP + p] = cfb[3];
                e[3 * NP + p] = Ab*cfb[3] + cfb[2];
                e[2 * NP + p] = Ab*cfb[2] + cfb[1];
                e[NP + p]     = Ab*cfb[1] + cfb[0];
                e[p]          = Ab*cfb[0];
            }
        }
        // roll: batch-0's next g_hpre is exactly g_h2
        if (k < 3)
            for (int o = t; o < 1536; o += 512) s_ghp[0][o] = s_gh2[o];
    }
}

// ---- mega helpers ----
__device__ __forceinline__ void rdcol(const float4* C4, int cc, float (&D)[28]) {
    const float4* s4 = C4 + cc * 9;
    #pragma unroll
    for (int j = 0; j < 7; ++j) {
        float4 v = s4[j];
        D[4*j] = v.x; D[4*j+1] = v.y; D[4*j+2] = v.z; D[4*j+3] = v.w;
    }
}
__device__ __forceinline__ void zcol(float (&D)[28]) {
    #pragma unroll
    for (int r = 0; r < 28; ++r) D[r] = 0.f;
}
__device__ __forceinline__ void wrcol(float4* C4, int cc, const float (&S)[28]) {
    #pragma unroll
    for (int j = 0; j < 7; ++j)
        C4[cc * 9 + j] = make_float4(S[4*j], S[4*j+1], S[4*j+2], S[4*j+3]);
}

// ---- mega: out = sum_j e_j K^j x0 via Horner; column registers, 2 planes/wave ----
__global__ void __launch_bounds__(256) mega_kernel(
        const float* __restrict__ x, float* __restrict__ out,
        const float* __restrict__ e, const float* __restrict__ dwk) {
    __shared__ float lds[8 * 1008];
    const int t = threadIdx.x;
    const int w = t >> 6, lane = t & 63;
    const int h = lane >> 5, c = lane & 31;
    const int pl = 2 * w + h;
    const int p = blockIdx.x * 8 + pl;
    const int ch = p & 511;
    const bool act = (c < 28);

    // stage wave's 2 planes: global f4 -> LDS row-major
    {
        const float4* xg = (const float4*)(x + (size_t)(blockIdx.x * 8 + 2 * w) * HW);
        float4* L = (float4*)(lds + 2 * w * 1008);
        #pragma unroll
        for (int i0 = 0; i0 < 7; ++i0) {
            int i = i0 * 64 + lane;
            if (i < 392) {
                int q = i / 196, rem = i - q * 196;
                int row = rem / 7, c4 = rem - row * 7;
                L[q * 252 + row * 7 + c4] = xg[i];
            }
        }
    }
    asm volatile("" ::: "memory");

    float e0 = e[p], e1 = e[NP + p], e2 = e[2 * NP + p], e3 = e[3 * NP + p], e4 = e[4 * NP + p];
    float w0 = dwk[ch*9+0], w1 = dwk[ch*9+1], w2 = dwk[ch*9+2];
    float w3 = dwk[ch*9+3], w4 = dwk[ch*9+4], w5 = dwk[ch*9+5];
    float w6 = dwk[ch*9+6], w7 = dwk[ch*9+7], w8 = dwk[ch*9+8];

    float* P = lds + pl * 1008;
    float4* C4 = (float4*)lds + pl * 252;

    float xr[28], tt[28], l[28], rr[28];

    if (act) {
        #pragma unroll
        for (int r = 0; r < 28; ++r) xr[r] = P[r * 28 + c];
    }
    asm volatile("" ::: "memory");
    if (act) wrcol(C4, c, xr);
    asm volatile("" ::: "memory");

    // iter 1: tt = e3*x + e4*K(x)
    if (act) {
        if (c > 0) rdcol(C4, c - 1, l); else zcol(l);
        if (c < 27) rdcol(C4, c + 1, rr); else zcol(rr);
        #pragma unroll
        for (int r = 0; r < 28; ++r) {
            float tm1 = (r > 0) ? xr[r-1] : 0.f, tp1 = (r < 27) ? xr[r+1] : 0.f;
            float lm1 = (r > 0) ? l[r-1]  : 0.f, lp1 = (r < 27) ? l[r+1]  : 0.f;
            float rm1 = (r > 0) ? rr[r-1] : 0.f, rp1 = (r < 27) ? rr[r+1] : 0.f;
            float tap = w0*lm1 + w1*tm1 + w2*rm1 + w3*l[r] + w4*xr[r] + w5*rr[r]
                      + w6*lp1 + w7*tp1 + w8*rp1;
            tt[r] = e3 * xr[r] + e4 * tap;
        }
    }
    asm volatile("" ::: "memory");
    if (act) wrcol(C4, c, tt);
    asm volatile("" ::: "memory");

    #pragma unroll
    for (int it = 2; it <= 4; ++it) {
        float ecur = (it == 2) ? e2 : (it == 3) ? e1 : e0;
        if (act) {
            if (c > 0) rdcol(C4, c - 1, l); else zcol(l);
            if (c < 27) rdcol(C4, c + 1, rr); else zcol(rr);
            float pm1 = 0.f;
            #pragma unroll
            for (int r = 0; r < 28; ++r) {
                float cur = tt[r];
                float tp1 = (r < 27) ? tt[r+1] : 0.f;
                float lm1 = (r > 0) ? l[r-1]  : 0.f, lp1 = (r < 27) ? l[r+1]  : 0.f;
                float rm1 = (r > 0) ? rr[r-1] : 0.f, rp1 = (r < 27) ? rr[r+1] : 0.f;
                float tap = w0*lm1 + w1*pm1 + w2*rm1 + w3*l[r] + w4*cur + w5*rr[r]
                          + w6*lp1 + w7*tp1 + w8*rp1;
                tt[r] = ecur * xr[r] + tap;
                pm1 = cur;
            }
        }
        asm volatile("" ::: "memory");
        if (it < 4) {
            if (act) wrcol(C4, c, tt);
            asm volatile("" ::: "memory");
        }
    }

    if (act) {
        #pragma unroll
        for (int r = 0; r < 28; ++r) P[r * 28 + c] = tt[r];
    }
    asm volatile("" ::: "memory");
    {
        float4* og = (float4*)(out + (size_t)(blockIdx.x * 8 + 2 * w) * HW);
        const float4* L = (const float4*)(lds + 2 * w * 1008);
        #pragma unroll
        for (int i0 = 0; i0 < 7; ++i0) {
            int i = i0 * 64 + lane;
            if (i < 392) {
                int q = i / 196, rem = i - q * 196;
                int row = rem / 7, c4 = rem - row * 7;
                og[i] = L[q * 252 + row * 7 + c4];
            }
        }
    }
}

extern "C" void kernel_launch(void* const* d_in, const int* in_sizes, int n_in,
                              void* d_out, int out_size, void* d_ws, size_t ws_size,
                              hipStream_t stream) {
    const float* x_in  = (const float*)d_in[0];
    const float* w_ih1 = (const float*)d_in[1];
    const float* b_ih1 = (const float*)d_in[2];
    const float* w_ih2 = (const float*)d_in[3];
    const float* b_ih2 = (const float*)d_in[4];
    const float* w_hh1 = (const float*)d_in[5];
    const float* b_hh1 = (const float*)d_in[6];
    const float* w_hh2 = (const float*)d_in[7];
    const float* b_hh2 = (const float*)d_in[8];
    const float* dwk   = (const float*)d_in[9];
    float* out = (float*)d_out;
    char* ws = (char*)d_ws;

    float* mu = (float*)(ws + 0);        // 4*NP*4 = 524288 B
    float* e  = (float*)(ws + 524288);   // 5*NP*4 = 655360 B

    statsW_kernel<<<1024, 256, 0, stream>>>(x_in, dwk, mu);
    cell_all_kernel<<<BB, 512, 0, stream>>>(mu, e, w_ih1, b_ih1, w_ih2, b_ih2,
                                            w_hh1, b_hh1, w_hh2, b_hh2);
    mega_kernel<<<4096, 256, 0, stream>>>(x_in, out, e, dwk);
}